// Round 6
// baseline (27.044 us; speedup 1.0000x reference)
//
#include <hip/hip_runtime.h>
#include <math.h>

#define NN 2048
#define RR 10
#define MM 2048
#define CC 84
#define NB 64          // cx bins over [0, 1000]
#define IEPS 1e-7f

// Monotone bin function — MUST be identical in setup and match kernels.
__device__ __forceinline__ int bin_of(float v) {
  int b = (int)floorf(v * 0.064f);   // 64 / 1000
  return min(NB - 1, max(0, b));
}

// Setup: per r, counting-sort dropout boxes by cx bin. One block per r.
// Also records max box width per r (window radius for exact pruning).
// Every output written fresh each call -> graph-replay safe, no memset.
__global__ __launch_bounds__(1024) void setup_kernel(
    const float* __restrict__ dpreds,
    float4* __restrict__ bbox, int* __restrict__ bidx,
    int* __restrict__ off, float* __restrict__ maxw) {
  __shared__ int cnt[NB];
  __shared__ int cur[NB];
  __shared__ unsigned wmax_sh;
  int r = blockIdx.x;
  int t = threadIdx.x;
  if (t < NB) cnt[t] = 0;
  if (t == 0) wmax_sh = 0u;
  __syncthreads();

  const float4* dp = reinterpret_cast<const float4*>(dpreds + (size_t)r * MM * 4);
  float4 bx[MM / 1024];
  int bn[MM / 1024];
  float wm = 0.0f;
#pragma unroll
  for (int k = 0; k < MM / 1024; ++k) {
    float4 d = dp[t + k * 1024];
    bx[k] = d;
    bn[k] = bin_of(d.x);
    atomicAdd(&cnt[bn[k]], 1);
    wm = fmaxf(wm, d.z);
  }
  atomicMax(&wmax_sh, __float_as_uint(wm));  // widths > 0 -> bit-monotone
  __syncthreads();

  if (t < 64) {  // wave 0: exclusive scan of 64 bins
    int c = cnt[t];
    int inc = c;
#pragma unroll
    for (int o = 1; o < 64; o <<= 1) {
      int x = __shfl_up(inc, o);
      if (t >= o) inc += x;
    }
    cur[t] = inc - c;                       // exclusive
    off[r * (NB + 1) + t + 1] = inc;        // inclusive -> off[b+1]
    if (t == 0) {
      off[r * (NB + 1)] = 0;
      maxw[r] = __uint_as_float(wmax_sh);
    }
  }
  __syncthreads();

#pragma unroll
  for (int k = 0; k < MM / 1024; ++k) {
    int slot = atomicAdd(&cur[bn[k]], 1);
    bbox[(size_t)r * MM + slot] = bx[k];
    bidx[(size_t)r * MM + slot] = t + k * 1024;
  }
}

// Match: one wave per (n, r). Test only the binned candidate range covering
// |cx_d - cx_p| <= w_p/2 + maxw_d/2 + 0.5 (provably brackets all iw>0 boxes).
// first_idx = min m among hits (== argmax-of-bool), -1 if none.
// Division-free: inter/(a1+a2-inter+eps) > 0.5 <=> 3*inter > a1+a2+eps.
__global__ __launch_bounds__(256) void match_kernel(
    const float* __restrict__ pred,
    const float4* __restrict__ bbox, const int* __restrict__ bidx,
    const int* __restrict__ off, const float* __restrict__ maxw,
    int* __restrict__ first_idx) {
  int wid = (blockIdx.x * blockDim.x + threadIdx.x) >> 6;
  int lane = threadIdx.x & 63;
  int n = wid & (NN - 1);
  int r = wid >> 11;   // NN = 1<<11

  float4 pb = *reinterpret_cast<const float4*>(pred + (size_t)n * CC);
  const float b1x1 = fmaf(-0.5f, pb.z, pb.x), b1x2 = fmaf(0.5f, pb.z, pb.x);
  const float b1y1 = fmaf(-0.5f, pb.w, pb.y), b1y2 = fmaf(0.5f, pb.w, pb.y);
  const float a1e = pb.z * pb.w + IEPS;  // area1 + eps

  float R = fmaf(0.5f, maxw[r], fmaf(0.5f, pb.z, 0.5f));
  int blo = bin_of(pb.x - R);
  int bhi = bin_of(pb.x + R);
  int start = off[r * (NB + 1) + blo];
  int end = off[r * (NB + 1) + bhi + 1];
  int len = end - start;

  const float4* __restrict__ bb = bbox + (size_t)r * MM;
  const int* __restrict__ bi = bidx + (size_t)r * MM;

  int best = 0x7FFFFFFF;
  for (int base = 0; base < len; base += 256) {
    int last = len - 1;
    int i0 = base + lane;
    int c0 = start + min(i0, last);
    int c1 = start + min(i0 + 64, last);
    int c2 = start + min(i0 + 128, last);
    int c3 = start + min(i0 + 192, last);
    float4 d0 = bb[c0];
    float4 d1 = bb[c1];
    float4 d2 = bb[c2];
    float4 d3 = bb[c3];

#define HIT(db, idx, valid)                                                 \
    {                                                                       \
      float x1 = fmaf(-0.5f, db.z, db.x), x2 = fmaf(0.5f, db.z, db.x);      \
      float y1 = fmaf(-0.5f, db.w, db.y), y2 = fmaf(0.5f, db.w, db.y);      \
      float iw = fmaxf(fminf(b1x2, x2) - fmaxf(b1x1, x1), 0.0f);            \
      float ih = fmaxf(fminf(b1y2, y2) - fmaxf(b1y1, y1), 0.0f);            \
      float inter = iw * ih;                                                \
      float tt = fmaf(db.z, db.w, a1e);                                     \
      if ((3.0f * inter > tt) && (valid)) best = min(best, bi[idx]);        \
    }
    HIT(d0, c0, i0 < len)
    HIT(d1, c1, i0 + 64 < len)
    HIT(d2, c2, i0 + 128 < len)
    HIT(d3, c3, i0 + 192 < len)
#undef HIT
  }

#pragma unroll
  for (int o = 32; o >= 1; o >>= 1) best = min(best, __shfl_xor(best, o));
  if (lane == 0) first_idx[n * RR + r] = (best == 0x7FFFFFFF) ? -1 : best;
}

// Entropy: one wave per n. Lane l handles classes l and l+64 (C=84).
__global__ __launch_bounds__(256) void entropy_kernel(
    const float* __restrict__ confs,
    const int* __restrict__ first_idx,
    float* __restrict__ out) {
  int lane = threadIdx.x & 63;
  int n = blockIdx.x * (blockDim.x >> 6) + (threadIdx.x >> 6);
  if (n >= NN) return;

  int idxs[RR];
  bool anym = false;
#pragma unroll
  for (int r = 0; r < RR; ++r) {
    idxs[r] = first_idx[n * RR + r];
    anym = anym || (idxs[r] >= 0);
  }

  const bool has_hi = (lane + 64) < CC;
  float e0 = 0.0f, e1 = 0.0f;
#pragma unroll
  for (int r = 0; r < RR; ++r) {
    if (idxs[r] >= 0) {
      const float* row = confs + ((size_t)r * MM + (size_t)idxs[r]) * CC;
      float p0 = row[lane];
      e0 -= p0 * __logf(p0);
      if (has_hi) {
        float p1 = row[lane + 64];
        e1 -= p1 * __logf(p1);
      }
    }
  }

  float maxE = fmaxf(e0, has_hi ? e1 : -INFINITY);
  float minE = fminf(e0, has_hi ? e1 : INFINITY);
#pragma unroll
  for (int o = 32; o >= 1; o >>= 1) {
    maxE = fmaxf(maxE, __shfl_xor(maxE, o));
    minE = fminf(minE, __shfl_xor(minE, o));
  }
  float s = __expf(e0 - maxE) + (has_hi ? __expf(e1 - maxE) : 0.0f);
#pragma unroll
  for (int o = 32; o >= 1; o >>= 1) s += __shfl_xor(s, o);

  float result = anym ? (1.0f - __expf(minE - maxE) / s) : nanf("");
  if (lane == 0) out[n] = result;
}

extern "C" void kernel_launch(void* const* d_in, const int* in_sizes, int n_in,
                              void* d_out, int out_size, void* d_ws, size_t ws_size,
                              hipStream_t stream) {
  const float* pred   = (const float*)d_in[0];   // (N, 84)
  const float* dpreds = (const float*)d_in[1];   // (R, M, 4)
  const float* confs  = (const float*)d_in[2];   // (R, M, 84)
  float* out = (float*)d_out;                    // (N,)

  // Workspace layout (16B-aligned chunks)
  char* ws = (char*)d_ws;
  float4* bbox     = (float4*)ws;                               // 10*2048*16
  int*    bidx     = (int*)(ws + (size_t)RR * MM * 16);         // 10*2048*4
  int*    firstidx = bidx + RR * MM;                            // 20480*4
  int*    off      = firstidx + NN * RR;                        // 10*65*4
  float*  maxw     = (float*)(off + RR * (NB + 1));             // 10*4

  setup_kernel<<<RR, 1024, 0, stream>>>(dpreds, bbox, bidx, off, maxw);
  match_kernel<<<NN * RR / 4, 256, 0, stream>>>(pred, bbox, bidx, off, maxw,
                                                firstidx);
  entropy_kernel<<<(NN + 3) / 4, 256, 0, stream>>>(confs, firstidx, out);
}

// Round 7
// 23.929 us; speedup vs baseline: 1.1302x; 1.1302x over previous
//
#include <hip/hip_runtime.h>
#include <math.h>

#define NN 2048
#define RR 10
#define MM 2048
#define CC 84
#define IEPS 1e-7f

// Single fused kernel. Block n (640 threads = 10 waves):
//   wave r: early-exit ballot scan of dpreds[r] vs pred[n] -> first-hit m
//           (first set bit in m-order == argmax-of-bool), idx -> LDS.
//   syncthreads; wave 0: entropy over matched r, softmax over 84 classes,
//   out[n] = 1 - max softmax-complement, NaN if no r matched.
// Division-free IoU: inter/(a1+a2-inter+eps) > 0.5 <=> 3*inter > a1+a2+eps.
__global__ __launch_bounds__(640) void fused_kernel(
    const float* __restrict__ pred,
    const float* __restrict__ dpreds,
    const float* __restrict__ confs,
    float* __restrict__ out) {
  __shared__ int sidx[RR];

  const int n = blockIdx.x;
  const int r = threadIdx.x >> 6;   // wave in block = dropout replicate
  const int lane = threadIdx.x & 63;

  // ---- Match phase (all 10 waves in parallel) ----
  float4 pb = *reinterpret_cast<const float4*>(pred + (size_t)n * CC);
  const float b1x1 = fmaf(-0.5f, pb.z, pb.x), b1x2 = fmaf(0.5f, pb.z, pb.x);
  const float b1y1 = fmaf(-0.5f, pb.w, pb.y), b1y2 = fmaf(0.5f, pb.w, pb.y);
  const float a1e = pb.z * pb.w + IEPS;  // area1 + eps

  const float4* __restrict__ dp =
      reinterpret_cast<const float4*>(dpreds + (size_t)r * MM * 4);

  int found = -1;
  for (int m0 = 0; m0 < MM; m0 += 256) {
    float4 d0 = dp[m0 + lane];
    float4 d1 = dp[m0 + 64 + lane];
    float4 d2 = dp[m0 + 128 + lane];
    float4 d3 = dp[m0 + 192 + lane];

#define HIT(db, h)                                                          \
    {                                                                       \
      float x1 = fmaf(-0.5f, db.z, db.x), x2 = fmaf(0.5f, db.z, db.x);      \
      float y1 = fmaf(-0.5f, db.w, db.y), y2 = fmaf(0.5f, db.w, db.y);      \
      float iw = fmaxf(fminf(b1x2, x2) - fmaxf(b1x1, x1), 0.0f);            \
      float ih = fmaxf(fminf(b1y2, y2) - fmaxf(b1y1, y1), 0.0f);            \
      float inter = iw * ih;                                                \
      float t = fmaf(db.z, db.w, a1e); /* a2 + a1 + eps */                  \
      h = (3.0f * inter > t);                                               \
    }
    bool h0, h1, h2, h3;
    HIT(d0, h0) HIT(d1, h1) HIT(d2, h2) HIT(d3, h3)
#undef HIT

    unsigned long long b0 = __ballot(h0);
    unsigned long long b1 = __ballot(h1);
    unsigned long long b2 = __ballot(h2);
    unsigned long long b3 = __ballot(h3);
    if (b0 | b1 | b2 | b3) {
      if (b0)      found = m0 +       (__ffsll(b0) - 1);
      else if (b1) found = m0 + 64  + (__ffsll(b1) - 1);
      else if (b2) found = m0 + 128 + (__ffsll(b2) - 1);
      else         found = m0 + 192 + (__ffsll(b3) - 1);
      break;
    }
  }
  if (lane == 0) sidx[r] = found;
  __syncthreads();

  // ---- Entropy phase (wave 0 only; ~20 loads + 20 logs + shuffles) ----
  if (r == 0) {
    int idxs[RR];
    bool anym = false;
#pragma unroll
    for (int q = 0; q < RR; ++q) {
      idxs[q] = sidx[q];
      anym = anym || (idxs[q] >= 0);
    }

    const bool has_hi = (lane + 64) < CC;  // lanes 0..19 carry a 2nd class
    float e0 = 0.0f, e1 = 0.0f;
#pragma unroll
    for (int q = 0; q < RR; ++q) {
      if (idxs[q] >= 0) {
        const float* row = confs + ((size_t)q * MM + (size_t)idxs[q]) * CC;
        float p0 = row[lane];
        e0 -= p0 * __logf(p0);
        if (has_hi) {
          float p1 = row[lane + 64];
          e1 -= p1 * __logf(p1);
        }
      }
    }

    float maxE = fmaxf(e0, has_hi ? e1 : -INFINITY);
    float minE = fminf(e0, has_hi ? e1 : INFINITY);
#pragma unroll
    for (int o = 32; o >= 1; o >>= 1) {
      maxE = fmaxf(maxE, __shfl_xor(maxE, o));
      minE = fminf(minE, __shfl_xor(minE, o));
    }
    float s = __expf(e0 - maxE) + (has_hi ? __expf(e1 - maxE) : 0.0f);
#pragma unroll
    for (int o = 32; o >= 1; o >>= 1) s += __shfl_xor(s, o);

    float result = anym ? (1.0f - __expf(minE - maxE) / s) : nanf("");
    if (lane == 0) out[n] = result;
  }
}

extern "C" void kernel_launch(void* const* d_in, const int* in_sizes, int n_in,
                              void* d_out, int out_size, void* d_ws, size_t ws_size,
                              hipStream_t stream) {
  const float* pred   = (const float*)d_in[0];   // (N, 84)
  const float* dpreds = (const float*)d_in[1];   // (R, M, 4)
  const float* confs  = (const float*)d_in[2];   // (R, M, 84)
  float* out = (float*)d_out;                    // (N,)

  fused_kernel<<<NN, 640, 0, stream>>>(pred, dpreds, confs, out);
}